// Round 17
// baseline (1364.313 us; speedup 1.0000x reference)
//
#include <hip/hip_runtime.h>
#include <math.h>

#define Cdim   256
#define Ssp    8192      // D*H*W
#define Npts   65536
#define NCODES 1024
#define BETA   0.25f
#define MT     128       // points per GEMM block
#define ESCALE 8192.0f   // keep el out of f16-subnormal truncation
#define WS_NEED (65536 + (size_t)786432 * 2)
#define ABL_OFF (65536 + 1048576)            // scratch for ablation outputs (within WS_NEED)

typedef _Float16 f16;
typedef f16   half8  __attribute__((ext_vector_type(8)));
typedef float f32x16 __attribute__((ext_vector_type(16)));

#define MFMA16(A, B, C) __builtin_amdgcn_mfma_f32_32x32x16_f16(A, B, C, 0, 0, 0)

__device__ __forceinline__ void keep(half8 x) { asm volatile("" :: "v"(x)); }

// ---------------- embed norms ----------------
__global__ __launch_bounds__(256) void enorm_kernel(const float* __restrict__ embed,
                                                    float* __restrict__ enorm) {
    int j = blockIdx.x * 256 + threadIdx.x;
    if (j >= NCODES) return;
    const float4* row = reinterpret_cast<const float4*>(embed + (size_t)j * Cdim);
    float s = 0.f;
#pragma unroll 8
    for (int c4 = 0; c4 < Cdim / 4; ++c4) {
        float4 v = row[c4];
        s += v.x * v.x + v.y * v.y + v.z * v.z + v.w * v.w;
    }
    enorm[j] = s;
}

// ---------------- prep: split embed into f16 hi/lo, chunk-tiled ----------------
// Bws: [kc=32][code=1024][k'=16] f16. kc 0..15 -> eh, kc 16..31 -> el. (r16, verified)
__global__ __launch_bounds__(256) void prep_kernel(const float* __restrict__ embed,
                                                   f16* __restrict__ Bws) {
    int tid = blockIdx.x * 256 + threadIdx.x;
    int o4 = tid * 4;
    int kc = o4 >> 14;
    int r  = o4 & 16383;
    int j  = r >> 4;
    int k0 = r & 15;
#pragma unroll
    for (int i = 0; i < 4; ++i) {
        int k = kc * 16 + k0 + i;
        int c = k & 255;
        float ev = embed[j * 256 + c] * ESCALE;
        f16 eh = (f16)ev;
        f16 v  = (k >= 256) ? (f16)(ev - (float)eh) : eh;
        Bws[o4 + i] = v;
    }
}

// ---------------- MFMA GEMM + fused argmin + loss (r16 body, templated ablation) ----------------
// V=0: full (real outputs). V=1: B loads removed (constant B). V=2: A ds_reads
// removed (constant A). V=3: MFMAs removed (operands kept live via asm).
// V!=0 variants run on 256 blocks and write to dead scratch — pure diagnostics.
template<int V>
__global__ __launch_bounds__(512, 2) void vq_gemm(const float* __restrict__ z,
                                                  const f16* __restrict__ Bws,
                                                  const float* __restrict__ enorm,
                                                  float* __restrict__ out_idx,
                                                  float* __restrict__ loss_acc,
                                                  float* __restrict__ counts) {
    __shared__ __attribute__((aligned(16))) f16 As[MT * 512];   // 128 KB
    __shared__ float en_s[NCODES];
    __shared__ float znp[4 * MT];
    __shared__ float zn_s[MT];
    __shared__ float redv[8 * MT];
    __shared__ int   redi[8 * MT];

    const int t  = threadIdx.x;
    const int l  = t & 63;
    const int w  = t >> 6;
    const int wm = w >> 2;
    const int wn = w & 3;
    const int ln = l & 31;
    const int kb = l >> 5;
    const int n0 = blockIdx.x * MT;
    const int b  = n0 >> 13;
    const int s0 = n0 & 8191;

    const half8 cK = {(f16)1, (f16)1, (f16)1, (f16)1, (f16)1, (f16)1, (f16)1, (f16)1};

    // ---- stage A (zh granules 0..31, zl 32..63, swizzle g^=(p&7)) ----
    {
        const int p = t & 127;
        const int q = t >> 7;
        const float* zb = z + (size_t)b * ((size_t)Cdim * Ssp) + s0;
        float zsq = 0.f;
#pragma unroll
        for (int gi = 0; gi < 8; ++gi) {
            const int c0 = q * 64 + gi * 8;
            half8 hh, ll;
#pragma unroll
            for (int u = 0; u < 8; ++u) {     // c ascending -> zsq order == rounds 2/5-16
                float zv = zb[(size_t)(c0 + u) * Ssp + p];
                zsq += zv * zv;
                f16 zh = (f16)zv;
                hh[u] = zh;
                ll[u] = (f16)(zv - (float)zh);
            }
            const int g0 = c0 >> 3;
            *(half8*)&As[p * 512 + 8 * (g0 ^ (p & 7))]        = hh;
            *(half8*)&As[p * 512 + 8 * ((32 + g0) ^ (p & 7))] = ll;
        }
        znp[q * MT + p] = zsq;
    }
    for (int i = t; i < NCODES; i += 512) en_s[i] = enorm[i];
    __syncthreads();
    if (t < MT)
        zn_s[t] = ((znp[t] + znp[MT + t]) + znp[2 * MT + t]) + znp[3 * MT + t];
    __syncthreads();

    const int rowA = wm * 64 + ln;

#define LOADGE(kcv, H0, H1, L0, L1, B0, B1, B2, B3)                      \
    {                                                                    \
        const int kcl_ = ((kcv) < 16) ? (kcv) : 15;                      \
        const int gz   = 2 * kcl_ + kb;                                  \
        (void)gz;                                                        \
        if constexpr (V != 2) {                                          \
            const int gwh = 8 * (gz ^ (ln & 7));                         \
            const int gwl = 8 * ((32 + gz) ^ (ln & 7));                  \
            H0 = *(const half8*)&As[rowA * 512 + gwh];                   \
            H1 = *(const half8*)&As[(rowA + 32) * 512 + gwh];            \
            L0 = *(const half8*)&As[rowA * 512 + gwl];                   \
            L1 = *(const half8*)&As[(rowA + 32) * 512 + gwl];            \
        } else { H0 = cK; H1 = cK; L0 = cK; L1 = cK; }                   \
        if constexpr (V != 1) {                                          \
            const f16* srcx = bbase + (size_t)kcl_ * 16384;              \
            B0 = *(const half8*)(srcx);                                  \
            B1 = *(const half8*)(srcx + 512);                            \
            B2 = *(const half8*)(srcx + 1024);                           \
            B3 = *(const half8*)(srcx + 1536);                           \
        } else { B0 = cK; B1 = cK; B2 = cK; B3 = cK; }                   \
    }

#define MFMAGE(H0, H1, L0, L1, B0, B1, B2, B3)                           \
    if constexpr (V == 3) {                                              \
        keep(H0); keep(H1); keep(L0); keep(L1);                          \
        keep(B0); keep(B1); keep(B2); keep(B3);                          \
    } else {                                                             \
        __builtin_amdgcn_s_setprio(1);                                   \
        acc[0][0] = MFMA16(H0, B0, acc[0][0]);                           \
        acc[1][0] = MFMA16(H1, B0, acc[1][0]);                           \
        acc[0][1] = MFMA16(H0, B1, acc[0][1]);                           \
        acc[1][1] = MFMA16(H1, B1, acc[1][1]);                           \
        acc[0][2] = MFMA16(H0, B2, acc[0][2]);                           \
        acc[1][2] = MFMA16(H1, B2, acc[1][2]);                           \
        acc[0][3] = MFMA16(H0, B3, acc[0][3]);                           \
        acc[1][3] = MFMA16(H1, B3, acc[1][3]);                           \
        acc[0][0] = MFMA16(L0, B0, acc[0][0]);                           \
        acc[1][0] = MFMA16(L1, B0, acc[1][0]);                           \
        acc[0][1] = MFMA16(L0, B1, acc[0][1]);                           \
        acc[1][1] = MFMA16(L1, B1, acc[1][1]);                           \
        acc[0][2] = MFMA16(L0, B2, acc[0][2]);                           \
        acc[1][2] = MFMA16(L1, B2, acc[1][2]);                           \
        acc[0][3] = MFMA16(L0, B3, acc[0][3]);                           \
        acc[1][3] = MFMA16(L1, B3, acc[1][3]);                           \
        __builtin_amdgcn_s_setprio(0);                                   \
    }

#define LOADGL(kcv, A0, A1, B0, B1, B2, B3)                              \
    {                                                                    \
        const int kcl_ = ((kcv) < 32) ? (kcv) : 31;                      \
        const int gz   = 2 * (kcl_ - 16) + kb;                           \
        (void)gz;                                                        \
        if constexpr (V != 2) {                                          \
            const int gwh = 8 * (gz ^ (ln & 7));                         \
            A0 = *(const half8*)&As[rowA * 512 + gwh];                   \
            A1 = *(const half8*)&As[(rowA + 32) * 512 + gwh];            \
        } else { A0 = cK; A1 = cK; }                                     \
        if constexpr (V != 1) {                                          \
            const f16* srcx = bbase + (size_t)kcl_ * 16384;              \
            B0 = *(const half8*)(srcx);                                  \
            B1 = *(const half8*)(srcx + 512);                            \
            B2 = *(const half8*)(srcx + 1024);                           \
            B3 = *(const half8*)(srcx + 1536);                           \
        } else { B0 = cK; B1 = cK; B2 = cK; B3 = cK; }                   \
    }

#define MFMAGL(A0, A1, B0, B1, B2, B3)                                   \
    if constexpr (V == 3) {                                              \
        keep(A0); keep(A1); keep(B0); keep(B1); keep(B2); keep(B3);      \
    } else {                                                             \
        __builtin_amdgcn_s_setprio(1);                                   \
        acc[0][0] = MFMA16(A0, B0, acc[0][0]);                           \
        acc[1][0] = MFMA16(A1, B0, acc[1][0]);                           \
        acc[0][1] = MFMA16(A0, B1, acc[0][1]);                           \
        acc[1][1] = MFMA16(A1, B1, acc[1][1]);                           \
        acc[0][2] = MFMA16(A0, B2, acc[0][2]);                           \
        acc[1][2] = MFMA16(A1, B2, acc[1][2]);                           \
        acc[0][3] = MFMA16(A0, B3, acc[0][3]);                           \
        acc[1][3] = MFMA16(A1, B3, acc[1][3]);                           \
        __builtin_amdgcn_s_setprio(0);                                   \
    }

#define SB __builtin_amdgcn_sched_barrier(0);

#pragma unroll 1
    for (int jh = 0; jh < 2; ++jh) {
        f32x16 acc[2][4] = {};
        const f16* bbase = Bws + (size_t)(jh * 512 + wn * 128 + ln) * 16 + kb * 8;

        // ===== phase E: eh chunks 0..15, 16 MFMAs each (B reused zh+zl) =====
        {
            half8 hA0, hA1, lA0, lA1, bA0, bA1, bA2, bA3;
            half8 hB0, hB1, lB0, lB1, bB0, bB1, bB2, bB3;
            LOADGE(0, hA0, hA1, lA0, lA1, bA0, bA1, bA2, bA3)
#pragma unroll 1
            for (int kc = 0; kc < 16; kc += 2) {
                LOADGE(kc + 1, hB0, hB1, lB0, lB1, bB0, bB1, bB2, bB3)
                SB
                MFMAGE(hA0, hA1, lA0, lA1, bA0, bA1, bA2, bA3)
                SB
                LOADGE(kc + 2, hA0, hA1, lA0, lA1, bA0, bA1, bA2, bA3)
                SB
                MFMAGE(hB0, hB1, lB0, lB1, bB0, bB1, bB2, bB3)
                SB
            }
        }
        // ===== phase L: el chunks 16..31, 8 MFMAs each (zh only) =====
        {
            half8 aA0, aA1, bA0, bA1, bA2, bA3;
            half8 aB0, aB1, bB0, bB1, bB2, bB3;
            LOADGL(16, aA0, aA1, bA0, bA1, bA2, bA3)
#pragma unroll 1
            for (int kc = 16; kc < 32; kc += 2) {
                LOADGL(kc + 1, aB0, aB1, bB0, bB1, bB2, bB3)
                SB
                MFMAGL(aA0, aA1, bA0, bA1, bA2, bA3)
                SB
                LOADGL(kc + 2, aA0, aA1, bA0, bA1, bA2, bA3)
                SB
                MFMAGL(aB0, aB1, bB0, bB1, bB2, bB3)
                SB
            }
        }

        // ---- scores + per-half argmin (verified rounds 5-16) ----
        const int h = l >> 5;
#pragma unroll
        for (int mm = 0; mm < 2; ++mm) {
#pragma unroll
            for (int rg = 0; rg < 16; ++rg) {
                const int row = wm * 64 + mm * 32 + (rg & 3) + 8 * (rg >> 2) + 4 * h;
                const float znv = zn_s[row];
                float bv = 3.0e38f; int bi = 0;
#pragma unroll
                for (int nn = 0; nn < 4; ++nn) {
                    const int col = jh * 512 + wn * 128 + nn * 32 + ln;
                    float k1 = znv + en_s[col];
                    float sc = k1 - acc[mm][nn][rg] * (2.0f / ESCALE);
                    if (sc < bv) { bv = sc; bi = col; }
                }
#pragma unroll
                for (int off = 1; off < 32; off <<= 1) {
                    float ov = __shfl_xor(bv, off, 64);
                    int   oi = __shfl_xor(bi, off, 64);
                    if (ov < bv || (ov == bv && oi < bi)) { bv = ov; bi = oi; }
                }
                if (ln == 0) {
                    redv[(jh * 4 + wn) * MT + row] = bv;
                    redi[(jh * 4 + wn) * MT + row] = bi;
                }
            }
        }
    }
    __syncthreads();

    // ---- final argmin; index/count; loss = sum of best scores ----
    if (t < MT) {
        float bv = redv[t]; int bi = redi[t];
#pragma unroll
        for (int s = 1; s < 8; ++s) {
            float ov = redv[s * MT + t]; int oi = redi[s * MT + t];
            if (ov < bv || (ov == bv && oi < bi)) { bv = ov; bi = oi; }
        }
        out_idx[n0 + t] = (float)bi;
        atomicAdd(&counts[bi], 1.0f);
        float lsum = bv;
#pragma unroll
        for (int off = 32; off > 0; off >>= 1) lsum += __shfl_down(lsum, off, 64);
        if ((t & 63) == 0) atomicAdd(loss_acc, lsum);
    }
#undef LOADGE
#undef MFMAGE
#undef LOADGL
#undef MFMAGL
#undef SB
}

// ---------------- epilogue: z_q gather-write only ----------------
__global__ __launch_bounds__(256) void vq_epi(const float* __restrict__ embed,
                                              const float* __restrict__ out_idx,
                                              float* __restrict__ out_zq) {
    const int n = blockIdx.x * 256 + threadIdx.x;
    const int b = n >> 13, s = n & 8191;
    const int idx = (int)out_idx[n];
    const float4* er = reinterpret_cast<const float4*>(embed + (size_t)idx * Cdim);
    float* oq = out_zq + (size_t)b * ((size_t)Cdim * Ssp) + s;
#pragma unroll 4
    for (int c4 = 0; c4 < Cdim / 4; ++c4) {
        float4 e = er[c4];
        const int c = c4 * 4;
        __builtin_nontemporal_store(e.x, oq + (size_t)(c + 0) * Ssp);
        __builtin_nontemporal_store(e.y, oq + (size_t)(c + 1) * Ssp);
        __builtin_nontemporal_store(e.z, oq + (size_t)(c + 2) * Ssp);
        __builtin_nontemporal_store(e.w, oq + (size_t)(c + 3) * Ssp);
    }
}

// ================= fallback (round-4 verified kernel, used if ws too small) =================
#define PTS 64
#define CT  128
#define KC  32
__global__ __launch_bounds__(256, 2) void vq_main_fb(const float* __restrict__ z,
                                                     const float* __restrict__ embed,
                                                     const float* __restrict__ enorm,
                                                     float* __restrict__ out_zq,
                                                     float* __restrict__ out_idx,
                                                     float* __restrict__ loss_acc,
                                                     float* __restrict__ counts) {
    __shared__ __attribute__((aligned(16))) float smem[Cdim * PTS + KC * CT];
    float* zt = smem;
    float* et = smem + Cdim * PTS;
    const int t  = threadIdx.x;
    const int n0 = blockIdx.x * PTS;
    const int b  = n0 >> 13;
    const int s0 = n0 & 8191;
    const float* zb = z + (size_t)b * Cdim * Ssp + s0;
    {
        const int p4 = (t & 15) * 4, crow = t >> 4;
#pragma unroll
        for (int it = 0; it < 16; ++it) {
            int c = it * 16 + crow;
            float4 v = *reinterpret_cast<const float4*>(zb + (size_t)c * Ssp + p4);
            *reinterpret_cast<float4*>(&zt[c * PTS + p4]) = v;
        }
    }
    __syncthreads();
    {
        const int p = t & 63, qq = t >> 6;
        float sacc = 0.f;
#pragma unroll 8
        for (int c = qq * 64; c < qq * 64 + 64; ++c) { float v = zt[c * PTS + p]; sacc += v * v; }
        et[qq * 64 + p] = sacc;
    }
    __syncthreads();
    const int pg = t & 15, jg = t >> 4;
    const int p0 = pg * 4;
    float zn[4];
#pragma unroll
    for (int i = 0; i < 4; ++i) {
        int p = p0 + i;
        zn[i] = ((et[p] + et[64 + p]) + et[128 + p]) + et[192 + p];
    }
    float bestv[4] = {3.0e38f, 3.0e38f, 3.0e38f, 3.0e38f};
    int   besti[4] = {0, 0, 0, 0};
    const int dj = t >> 3, q = t & 7;
    const int sw_st = (q & 3) << 3;
    for (int jt = 0; jt < NCODES / CT; ++jt) {
        const int J0 = jt * CT;
        float acc[4][8];
#pragma unroll
        for (int i = 0; i < 4; ++i)
#pragma unroll
            for (int m = 0; m < 8; ++m) acc[i][m] = 0.f;
        for (int ks = 0; ks < Cdim / KC; ++ks) {
            const int cc0 = ks * KC;
            __syncthreads();
#pragma unroll
            for (int i = 0; i < 4; ++i) {
                const int jrel = dj + 32 * i;
                const float4 v = *reinterpret_cast<const float4*>(
                    embed + (size_t)(J0 + jrel) * Cdim + cc0 + q * 4);
                const int c0 = q * 4;
                const int jsw = jrel ^ sw_st;
                et[(c0 + 0) * CT + jsw] = v.x;
                et[(c0 + 1) * CT + jsw] = v.y;
                et[(c0 + 2) * CT + jsw] = v.z;
                et[(c0 + 3) * CT + jsw] = v.w;
            }
            __syncthreads();
#pragma unroll 4
            for (int c = 0; c < KC; ++c) {
                const float4 zp = *reinterpret_cast<const float4*>(&zt[(cc0 + c) * PTS + p0]);
                const int jb = (jg * 8) ^ (((c >> 2) & 3) << 3);
                const float4 ea = *reinterpret_cast<const float4*>(&et[c * CT + jb]);
                const float4 eb = *reinterpret_cast<const float4*>(&et[c * CT + jb + 4]);
                const float zc[4] = {zp.x, zp.y, zp.z, zp.w};
                const float ec[8] = {ea.x, ea.y, ea.z, ea.w, eb.x, eb.y, eb.z, eb.w};
#pragma unroll
                for (int i = 0; i < 4; ++i)
#pragma unroll
                    for (int m = 0; m < 8; ++m) acc[i][m] += zc[i] * ec[m];
            }
        }
#pragma unroll
        for (int m = 0; m < 8; ++m) {
            const int cid = J0 + jg * 8 + m;
            const float en = enorm[cid];
#pragma unroll
            for (int i = 0; i < 4; ++i) {
                float k1 = zn[i] + en;
                float sc = k1 - 2.0f * acc[i][m];
                if (sc < bestv[i]) { bestv[i] = sc; besti[i] = cid; }
            }
        }
    }
    __syncthreads();
    float* rv = et; int* ri = (int*)(et + 1024); int* idxf = (int*)(et + 2048);
#pragma unroll
    for (int i = 0; i < 4; ++i) { int p = p0 + i; rv[p * 16 + jg] = bestv[i]; ri[p * 16 + jg] = besti[i]; }
    __syncthreads();
    if (t < PTS) {
        int p = t;
        float bv = rv[p * 16]; int bi = ri[p * 16];
        for (int g = 1; g < 16; ++g) {
            float v = rv[p * 16 + g]; int ii = ri[p * 16 + g];
            if (v < bv || (v == bv && ii < bi)) { bv = v; bi = ii; }
        }
        idxf[p] = bi;
        out_idx[n0 + p] = (float)bi;
        atomicAdd(&counts[bi], 1.0f);
    }
    __syncthreads();
    float lsum = 0.f;
    {
        const int p = t & 63, cbase = t >> 6;
        const int myidx = idxf[p];
        const float4* erow4 = reinterpret_cast<const float4*>(embed + (size_t)myidx * Cdim);
        float* ob = out_zq + (size_t)b * Cdim * Ssp + s0 + p;
#pragma unroll 4
        for (int pass = 0; pass < 16; ++pass) {
            int c = cbase * 64 + pass * 4;
            float4 e = erow4[c >> 2];
            ob[(size_t)(c + 0) * Ssp] = e.x;
            ob[(size_t)(c + 1) * Ssp] = e.y;
            ob[(size_t)(c + 2) * Ssp] = e.z;
            ob[(size_t)(c + 3) * Ssp] = e.w;
            float d0 = zt[(c + 0) * PTS + p] - e.x;
            float d1 = zt[(c + 1) * PTS + p] - e.y;
            float d2 = zt[(c + 2) * PTS + p] - e.z;
            float d3 = zt[(c + 3) * PTS + p] - e.w;
            lsum += d0 * d0 + d1 * d1 + d2 * d2 + d3 * d3;
        }
    }
#pragma unroll
    for (int off = 32; off > 0; off >>= 1) lsum += __shfl_down(lsum, off, 64);
    if ((t & 63) == 0) atomicAdd(loss_acc, lsum);
}

// ---------------- finalize ----------------
__global__ __launch_bounds__(1024) void vq_final(const float* __restrict__ counts,
                                                 const float* __restrict__ loss_acc,
                                                 float* __restrict__ out_loss,
                                                 float* __restrict__ out_perp) {
    __shared__ float red[16];
    int t = threadIdx.x;
    float cnt = counts[t];
    float avg = cnt * (1.0f / (float)Npts);
    float term = avg * logf(avg + 1e-10f);
#pragma unroll
    for (int off = 32; off > 0; off >>= 1) term += __shfl_down(term, off, 64);
    if ((t & 63) == 0) red[t >> 6] = term;
    __syncthreads();
    if (t == 0) {
        float s = 0.f;
        for (int i = 0; i < 16; ++i) s += red[i];
        *out_perp = expf(-s);
        *out_loss = BETA * loss_acc[0] * (1.0f / 16777216.0f);
    }
}

extern "C" void kernel_launch(void* const* d_in, const int* in_sizes, int n_in,
                              void* d_out, int out_size, void* d_ws, size_t ws_size,
                              hipStream_t stream) {
    const float* z     = (const float*)d_in[0];
    const float* embed = (const float*)d_in[1];

    float* ws       = (float*)d_ws;
    float* loss_acc = ws;            // [0]
    float* counts   = ws + 64;       // [1024]
    float* enorm    = ws + 2048;     // [1024]

    float* out_zq   = (float*)d_out;
    float* out_idx  = out_zq + (size_t)Npts * Cdim;
    float* out_loss = out_idx + Npts;
    float* out_perp = out_loss + 1;

    hipMemsetAsync(d_ws, 0, 2048 * sizeof(float), stream);
    enorm_kernel<<<NCODES / 256, 256, 0, stream>>>(embed, enorm);

    if (ws_size >= WS_NEED) {
        f16* Bws = (f16*)((char*)d_ws + 65536);
        prep_kernel<<<512, 256, 0, stream>>>(embed, Bws);   // 32 chunks = 1.0 MB
        // V0: real result, full grid
        vq_gemm<0><<<Npts / MT, 512, 0, stream>>>(z, Bws, enorm, out_idx,
                                                  loss_acc, counts);
        // diagnostics: 256-block ablations writing to dead scratch
        {
            float* abl      = (float*)((char*)d_ws + ABL_OFF);
            float* abl_idx  = abl;                // 32768 floats
            float* abl_loss = abl + 32768;        // 64
            float* abl_cnt  = abl + 32768 + 64;   // 1024
            vq_gemm<1><<<256, 512, 0, stream>>>(z, Bws, enorm, abl_idx, abl_loss, abl_cnt);
            vq_gemm<2><<<256, 512, 0, stream>>>(z, Bws, enorm, abl_idx, abl_loss, abl_cnt);
            vq_gemm<3><<<256, 512, 0, stream>>>(z, Bws, enorm, abl_idx, abl_loss, abl_cnt);
        }
        vq_epi<<<Npts / 256, 256, 0, stream>>>(embed, out_idx, out_zq);
    } else {
        vq_main_fb<<<Npts / PTS, 256, 0, stream>>>(z, embed, enorm, out_zq, out_idx,
                                                   loss_acc, counts);
    }
    vq_final<<<1, 1024, 0, stream>>>(counts, loss_acc, out_loss, out_perp);
}

// Round 18
// 189.437 us; speedup vs baseline: 7.2019x; 7.2019x over previous
//
#include <hip/hip_runtime.h>
#include <math.h>

#define Cdim   256
#define Ssp    8192      // D*H*W
#define Npts   65536
#define NCODES 1024
#define BETA   0.25f
#define MT     128       // points per GEMM block
#define ESCALE 8192.0f   // keep el out of f16-subnormal truncation
#define WS_NEED (65536 + (size_t)786432 * 2)

typedef _Float16 f16;
typedef f16   half8  __attribute__((ext_vector_type(8)));
typedef float f32x16 __attribute__((ext_vector_type(16)));

#define MFMA16(A, B, C) __builtin_amdgcn_mfma_f32_32x32x16_f16(A, B, C, 0, 0, 0)

// ---------------- enorm (standalone, used by fallback path only) ----------------
__global__ __launch_bounds__(256) void enorm_kernel(const float* __restrict__ embed,
                                                    float* __restrict__ enorm) {
    int j = blockIdx.x * 256 + threadIdx.x;
    if (j >= NCODES) return;
    const float4* row = reinterpret_cast<const float4*>(embed + (size_t)j * Cdim);
    float s = 0.f;
#pragma unroll 8
    for (int c4 = 0; c4 < Cdim / 4; ++c4) {
        float4 v = row[c4];
        s += v.x * v.x + v.y * v.y + v.z * v.z + v.w * v.w;
    }
    enorm[j] = s;
}

// ---------------- prep: split embed into f16 hi/lo + enorm + ws zero (fused) ----------------
// Bws: [kc=32][code=1024][k'=16] f16. kc 0..15 -> eh, kc 16..31 -> el. (r16, verified)
// Blocks 0..3 additionally compute enorm; block 4 zeroes loss_acc+counts.
__global__ __launch_bounds__(256) void prep_kernel(const float* __restrict__ embed,
                                                   f16* __restrict__ Bws,
                                                   float* __restrict__ enorm,
                                                   float* __restrict__ wszero) {
    int tid = blockIdx.x * 256 + threadIdx.x;
    int o4 = tid * 4;
    int kc = o4 >> 14;
    int r  = o4 & 16383;
    int j  = r >> 4;
    int k0 = r & 15;
#pragma unroll
    for (int i = 0; i < 4; ++i) {
        int k = kc * 16 + k0 + i;
        int c = k & 255;
        float ev = embed[j * 256 + c] * ESCALE;
        f16 eh = (f16)ev;
        f16 v  = (k >= 256) ? (f16)(ev - (float)eh) : eh;
        Bws[o4 + i] = v;
    }
    if (blockIdx.x < 4) {
        const int je = blockIdx.x * 256 + threadIdx.x;
        const float4* row = reinterpret_cast<const float4*>(embed + (size_t)je * Cdim);
        float s = 0.f;
#pragma unroll 8
        for (int c4 = 0; c4 < Cdim / 4; ++c4) {
            float4 v = row[c4];
            s += v.x * v.x + v.y * v.y + v.z * v.z + v.w * v.w;
        }
        enorm[je] = s;
    } else if (blockIdx.x == 4) {
        for (int i = threadIdx.x; i < 2048; i += 256) wszero[i] = 0.f;  // loss + counts
    }
}

// ---------------- MFMA GEMM + fused argmin + loss (r16 verified body) ----------------
// 512 thr / 8 waves (2m x 4n), MT=128, 2 jh halves, A=[zh|zl] 128KB LDS (XOR-swz),
// B global->reg pinned ping-pong + setprio. eh-reuse K split: per eh-chunk B frags
// serve both zh*eh and zl*eh (16 MFMAs/B-chunk); el phase does zh*el.
__global__ __launch_bounds__(512, 2) void vq_gemm(const float* __restrict__ z,
                                                  const f16* __restrict__ Bws,
                                                  const float* __restrict__ enorm,
                                                  float* __restrict__ out_idx,
                                                  float* __restrict__ loss_acc,
                                                  float* __restrict__ counts) {
    __shared__ __attribute__((aligned(16))) f16 As[MT * 512];   // 128 KB
    __shared__ float en_s[NCODES];
    __shared__ float znp[4 * MT];
    __shared__ float zn_s[MT];
    __shared__ float redv[8 * MT];
    __shared__ int   redi[8 * MT];

    const int t  = threadIdx.x;
    const int l  = t & 63;
    const int w  = t >> 6;
    const int wm = w >> 2;
    const int wn = w & 3;
    const int ln = l & 31;
    const int kb = l >> 5;
    const int n0 = blockIdx.x * MT;
    const int b  = n0 >> 13;
    const int s0 = n0 & 8191;

    // ---- stage A (zh granules 0..31, zl 32..63, swizzle g^=(p&7)) ----
    {
        const int p = t & 127;
        const int q = t >> 7;
        const float* zb = z + (size_t)b * ((size_t)Cdim * Ssp) + s0;
        float zsq = 0.f;
#pragma unroll
        for (int gi = 0; gi < 8; ++gi) {
            const int c0 = q * 64 + gi * 8;
            half8 hh, ll;
#pragma unroll
            for (int u = 0; u < 8; ++u) {     // c ascending -> zsq order == rounds 2/5-17
                float zv = zb[(size_t)(c0 + u) * Ssp + p];
                zsq += zv * zv;
                f16 zh = (f16)zv;
                hh[u] = zh;
                ll[u] = (f16)(zv - (float)zh);
            }
            const int g0 = c0 >> 3;
            *(half8*)&As[p * 512 + 8 * (g0 ^ (p & 7))]        = hh;
            *(half8*)&As[p * 512 + 8 * ((32 + g0) ^ (p & 7))] = ll;
        }
        znp[q * MT + p] = zsq;
    }
    for (int i = t; i < NCODES; i += 512) en_s[i] = enorm[i];
    __syncthreads();
    if (t < MT)
        zn_s[t] = ((znp[t] + znp[MT + t]) + znp[2 * MT + t]) + znp[3 * MT + t];
    __syncthreads();

    const int rowA = wm * 64 + ln;

#define LOADGE(kcv, H0, H1, L0, L1, B0, B1, B2, B3)                      \
    {                                                                    \
        const int kcl_ = ((kcv) < 16) ? (kcv) : 15;                      \
        const int gz   = 2 * kcl_ + kb;                                  \
        const int gwh  = 8 * (gz ^ (ln & 7));                            \
        const int gwl  = 8 * ((32 + gz) ^ (ln & 7));                     \
        H0 = *(const half8*)&As[rowA * 512 + gwh];                       \
        H1 = *(const half8*)&As[(rowA + 32) * 512 + gwh];                \
        L0 = *(const half8*)&As[rowA * 512 + gwl];                       \
        L1 = *(const half8*)&As[(rowA + 32) * 512 + gwl];                \
        const f16* srcx = bbase + (size_t)kcl_ * 16384;                  \
        B0 = *(const half8*)(srcx);                                      \
        B1 = *(const half8*)(srcx + 512);                                \
        B2 = *(const half8*)(srcx + 1024);                               \
        B3 = *(const half8*)(srcx + 1536);                               \
    }

#define MFMAGE(H0, H1, L0, L1, B0, B1, B2, B3)                           \
    __builtin_amdgcn_s_setprio(1);                                       \
    acc[0][0] = MFMA16(H0, B0, acc[0][0]);                               \
    acc[1][0] = MFMA16(H1, B0, acc[1][0]);                               \
    acc[0][1] = MFMA16(H0, B1, acc[0][1]);                               \
    acc[1][1] = MFMA16(H1, B1, acc[1][1]);                               \
    acc[0][2] = MFMA16(H0, B2, acc[0][2]);                               \
    acc[1][2] = MFMA16(H1, B2, acc[1][2]);                               \
    acc[0][3] = MFMA16(H0, B3, acc[0][3]);                               \
    acc[1][3] = MFMA16(H1, B3, acc[1][3]);                               \
    acc[0][0] = MFMA16(L0, B0, acc[0][0]);                               \
    acc[1][0] = MFMA16(L1, B0, acc[1][0]);                               \
    acc[0][1] = MFMA16(L0, B1, acc[0][1]);                               \
    acc[1][1] = MFMA16(L1, B1, acc[1][1]);                               \
    acc[0][2] = MFMA16(L0, B2, acc[0][2]);                               \
    acc[1][2] = MFMA16(L1, B2, acc[1][2]);                               \
    acc[0][3] = MFMA16(L0, B3, acc[0][3]);                               \
    acc[1][3] = MFMA16(L1, B3, acc[1][3]);                               \
    __builtin_amdgcn_s_setprio(0);

#define LOADGL(kcv, A0, A1, B0, B1, B2, B3)                              \
    {                                                                    \
        const int kcl_ = ((kcv) < 32) ? (kcv) : 31;                      \
        const int gz   = 2 * (kcl_ - 16) + kb;                           \
        const int gwh  = 8 * (gz ^ (ln & 7));                            \
        A0 = *(const half8*)&As[rowA * 512 + gwh];                       \
        A1 = *(const half8*)&As[(rowA + 32) * 512 + gwh];                \
        const f16* srcx = bbase + (size_t)kcl_ * 16384;                  \
        B0 = *(const half8*)(srcx);                                      \
        B1 = *(const half8*)(srcx + 512);                                \
        B2 = *(const half8*)(srcx + 1024);                               \
        B3 = *(const half8*)(srcx + 1536);                               \
    }

#define MFMAGL(A0, A1, B0, B1, B2, B3)                                   \
    __builtin_amdgcn_s_setprio(1);                                       \
    acc[0][0] = MFMA16(A0, B0, acc[0][0]);                               \
    acc[1][0] = MFMA16(A1, B0, acc[1][0]);                               \
    acc[0][1] = MFMA16(A0, B1, acc[0][1]);                               \
    acc[1][1] = MFMA16(A1, B1, acc[1][1]);                               \
    acc[0][2] = MFMA16(A0, B2, acc[0][2]);                               \
    acc[1][2] = MFMA16(A1, B2, acc[1][2]);                               \
    acc[0][3] = MFMA16(A0, B3, acc[0][3]);                               \
    acc[1][3] = MFMA16(A1, B3, acc[1][3]);                               \
    __builtin_amdgcn_s_setprio(0);

#define SB __builtin_amdgcn_sched_barrier(0);

#pragma unroll 1
    for (int jh = 0; jh < 2; ++jh) {
        f32x16 acc[2][4] = {};
        const f16* bbase = Bws + (size_t)(jh * 512 + wn * 128 + ln) * 16 + kb * 8;

        // ===== phase E: eh chunks 0..15, 16 MFMAs each (B reused zh+zl) =====
        {
            half8 hA0, hA1, lA0, lA1, bA0, bA1, bA2, bA3;
            half8 hB0, hB1, lB0, lB1, bB0, bB1, bB2, bB3;
            LOADGE(0, hA0, hA1, lA0, lA1, bA0, bA1, bA2, bA3)
#pragma unroll 1
            for (int kc = 0; kc < 16; kc += 2) {
                LOADGE(kc + 1, hB0, hB1, lB0, lB1, bB0, bB1, bB2, bB3)
                SB
                MFMAGE(hA0, hA1, lA0, lA1, bA0, bA1, bA2, bA3)
                SB
                LOADGE(kc + 2, hA0, hA1, lA0, lA1, bA0, bA1, bA2, bA3)
                SB
                MFMAGE(hB0, hB1, lB0, lB1, bB0, bB1, bB2, bB3)
                SB
            }
        }
        // ===== phase L: el chunks 16..31, 8 MFMAs each (zh only) =====
        {
            half8 aA0, aA1, bA0, bA1, bA2, bA3;
            half8 aB0, aB1, bB0, bB1, bB2, bB3;
            LOADGL(16, aA0, aA1, bA0, bA1, bA2, bA3)
#pragma unroll 1
            for (int kc = 16; kc < 32; kc += 2) {
                LOADGL(kc + 1, aB0, aB1, bB0, bB1, bB2, bB3)
                SB
                MFMAGL(aA0, aA1, bA0, bA1, bA2, bA3)
                SB
                LOADGL(kc + 2, aA0, aA1, bA0, bA1, bA2, bA3)
                SB
                MFMAGL(aB0, aB1, bB0, bB1, bB2, bB3)
                SB
            }
        }

        // ---- scores + per-half argmin. C layout: col=lane&31,
        //      row=(reg&3)+8*(reg>>2)+4*(lane>>5)  (verified rounds 5-17) ----
        const int h = l >> 5;
#pragma unroll
        for (int mm = 0; mm < 2; ++mm) {
#pragma unroll
            for (int rg = 0; rg < 16; ++rg) {
                const int row = wm * 64 + mm * 32 + (rg & 3) + 8 * (rg >> 2) + 4 * h;
                const float znv = zn_s[row];
                float bv = 3.0e38f; int bi = 0;
#pragma unroll
                for (int nn = 0; nn < 4; ++nn) {
                    const int col = jh * 512 + wn * 128 + nn * 32 + ln;
                    float k1 = znv + en_s[col];
                    float sc = k1 - acc[mm][nn][rg] * (2.0f / ESCALE);
                    if (sc < bv) { bv = sc; bi = col; }
                }
#pragma unroll
                for (int off = 1; off < 32; off <<= 1) {
                    float ov = __shfl_xor(bv, off, 64);
                    int   oi = __shfl_xor(bi, off, 64);
                    if (ov < bv || (ov == bv && oi < bi)) { bv = ov; bi = oi; }
                }
                if (ln == 0) {
                    redv[(jh * 4 + wn) * MT + row] = bv;
                    redi[(jh * 4 + wn) * MT + row] = bi;
                }
            }
        }
    }
    __syncthreads();

    // ---- final argmin; index/count; loss = sum of best scores ----
    if (t < MT) {
        float bv = redv[t]; int bi = redi[t];
#pragma unroll
        for (int s = 1; s < 8; ++s) {
            float ov = redv[s * MT + t]; int oi = redi[s * MT + t];
            if (ov < bv || (ov == bv && oi < bi)) { bv = ov; bi = oi; }
        }
        out_idx[n0 + t] = (float)bi;
        atomicAdd(&counts[bi], 1.0f);
        float lsum = bv;
#pragma unroll
        for (int off = 32; off > 0; off >>= 1) lsum += __shfl_down(lsum, off, 64);
        if ((t & 63) == 0) atomicAdd(loss_acc, lsum);
    }
#undef LOADGE
#undef MFMAGE
#undef LOADGL
#undef MFMAGL
#undef SB
}

// ---------------- epilogue: z_q gather-write, 4x wave-parallelism ----------------
// 1024 blocks x 256 thr; block owns 64 points; thread (p, cq) writes 64 c-values
// of point p. Stores coalesced over p (nt); embed gathers float4, L2-hot.
__global__ __launch_bounds__(256) void vq_epi(const float* __restrict__ embed,
                                              const float* __restrict__ out_idx,
                                              float* __restrict__ out_zq) {
    const int t  = threadIdx.x;
    const int n0 = blockIdx.x * 64;
    const int b  = n0 >> 13, s0 = n0 & 8191;
    const int p  = t & 63;
    const int cq = t >> 6;                  // 0..3, 64 c each
    const int idx = (int)out_idx[n0 + p];
    const float4* er = reinterpret_cast<const float4*>(embed + (size_t)idx * Cdim);
    float* oq = out_zq + (size_t)b * ((size_t)Cdim * Ssp) + s0 + p;
#pragma unroll 4
    for (int pass = 0; pass < 16; ++pass) {
        const int c = cq * 64 + pass * 4;
        float4 e = er[c >> 2];
        __builtin_nontemporal_store(e.x, oq + (size_t)(c + 0) * Ssp);
        __builtin_nontemporal_store(e.y, oq + (size_t)(c + 1) * Ssp);
        __builtin_nontemporal_store(e.z, oq + (size_t)(c + 2) * Ssp);
        __builtin_nontemporal_store(e.w, oq + (size_t)(c + 3) * Ssp);
    }
}

// ================= fallback (round-4 verified kernel, used if ws too small) =================
#define PTS 64
#define CT  128
#define KC  32
__global__ __launch_bounds__(256, 2) void vq_main_fb(const float* __restrict__ z,
                                                     const float* __restrict__ embed,
                                                     const float* __restrict__ enorm,
                                                     float* __restrict__ out_zq,
                                                     float* __restrict__ out_idx,
                                                     float* __restrict__ loss_acc,
                                                     float* __restrict__ counts) {
    __shared__ __attribute__((aligned(16))) float smem[Cdim * PTS + KC * CT];
    float* zt = smem;
    float* et = smem + Cdim * PTS;
    const int t  = threadIdx.x;
    const int n0 = blockIdx.x * PTS;
    const int b  = n0 >> 13;
    const int s0 = n0 & 8191;
    const float* zb = z + (size_t)b * Cdim * Ssp + s0;
    {
        const int p4 = (t & 15) * 4, crow = t >> 4;
#pragma unroll
        for (int it = 0; it < 16; ++it) {
            int c = it * 16 + crow;
            float4 v = *reinterpret_cast<const float4*>(zb + (size_t)c * Ssp + p4);
            *reinterpret_cast<float4*>(&zt[c * PTS + p4]) = v;
        }
    }
    __syncthreads();
    {
        const int p = t & 63, qq = t >> 6;
        float sacc = 0.f;
#pragma unroll 8
        for (int c = qq * 64; c < qq * 64 + 64; ++c) { float v = zt[c * PTS + p]; sacc += v * v; }
        et[qq * 64 + p] = sacc;
    }
    __syncthreads();
    const int pg = t & 15, jg = t >> 4;
    const int p0 = pg * 4;
    float zn[4];
#pragma unroll
    for (int i = 0; i < 4; ++i) {
        int p = p0 + i;
        zn[i] = ((et[p] + et[64 + p]) + et[128 + p]) + et[192 + p];
    }
    float bestv[4] = {3.0e38f, 3.0e38f, 3.0e38f, 3.0e38f};
    int   besti[4] = {0, 0, 0, 0};
    const int dj = t >> 3, q = t & 7;
    const int sw_st = (q & 3) << 3;
    for (int jt = 0; jt < NCODES / CT; ++jt) {
        const int J0 = jt * CT;
        float acc[4][8];
#pragma unroll
        for (int i = 0; i < 4; ++i)
#pragma unroll
            for (int m = 0; m < 8; ++m) acc[i][m] = 0.f;
        for (int ks = 0; ks < Cdim / KC; ++ks) {
            const int cc0 = ks * KC;
            __syncthreads();
#pragma unroll
            for (int i = 0; i < 4; ++i) {
                const int jrel = dj + 32 * i;
                const float4 v = *reinterpret_cast<const float4*>(
                    embed + (size_t)(J0 + jrel) * Cdim + cc0 + q * 4);
                const int c0 = q * 4;
                const int jsw = jrel ^ sw_st;
                et[(c0 + 0) * CT + jsw] = v.x;
                et[(c0 + 1) * CT + jsw] = v.y;
                et[(c0 + 2) * CT + jsw] = v.z;
                et[(c0 + 3) * CT + jsw] = v.w;
            }
            __syncthreads();
#pragma unroll 4
            for (int c = 0; c < KC; ++c) {
                const float4 zp = *reinterpret_cast<const float4*>(&zt[(cc0 + c) * PTS + p0]);
                const int jb = (jg * 8) ^ (((c >> 2) & 3) << 3);
                const float4 ea = *reinterpret_cast<const float4*>(&et[c * CT + jb]);
                const float4 eb = *reinterpret_cast<const float4*>(&et[c * CT + jb + 4]);
                const float zc[4] = {zp.x, zp.y, zp.z, zp.w};
                const float ec[8] = {ea.x, ea.y, ea.z, ea.w, eb.x, eb.y, eb.z, eb.w};
#pragma unroll
                for (int i = 0; i < 4; ++i)
#pragma unroll
                    for (int m = 0; m < 8; ++m) acc[i][m] += zc[i] * ec[m];
            }
        }
#pragma unroll
        for (int m = 0; m < 8; ++m) {
            const int cid = J0 + jg * 8 + m;
            const float en = enorm[cid];
#pragma unroll
            for (int i = 0; i < 4; ++i) {
                float k1 = zn[i] + en;
                float sc = k1 - 2.0f * acc[i][m];
                if (sc < bestv[i]) { bestv[i] = sc; besti[i] = cid; }
            }
        }
    }
    __syncthreads();
    float* rv = et; int* ri = (int*)(et + 1024); int* idxf = (int*)(et + 2048);
#pragma unroll
    for (int i = 0; i < 4; ++i) { int p = p0 + i; rv[p * 16 + jg] = bestv[i]; ri[p * 16 + jg] = besti[i]; }
    __syncthreads();
    if (t < PTS) {
        int p = t;
        float bv = rv[p * 16]; int bi = ri[p * 16];
        for (int g = 1; g < 16; ++g) {
            float v = rv[p * 16 + g]; int ii = ri[p * 16 + g];
            if (v < bv || (v == bv && ii < bi)) { bv = v; bi = ii; }
        }
        idxf[p] = bi;
        out_idx[n0 + p] = (float)bi;
        atomicAdd(&counts[bi], 1.0f);
    }
    __syncthreads();
    float lsum = 0.f;
    {
        const int p = t & 63, cbase = t >> 6;
        const int myidx = idxf[p];
        const float4* erow4 = reinterpret_cast<const float4*>(embed + (size_t)myidx * Cdim);
        float* ob = out_zq + (size_t)b * Cdim * Ssp + s0 + p;
#pragma unroll 4
        for (int pass = 0; pass < 16; ++pass) {
            int c = cbase * 64 + pass * 4;
            float4 e = erow4[c >> 2];
            ob[(size_t)(c + 0) * Ssp] = e.x;
            ob[(size_t)(c + 1) * Ssp] = e.y;
            ob[(size_t)(c + 2) * Ssp] = e.z;
            ob[(size_t)(c + 3) * Ssp] = e.w;
            float d0 = zt[(c + 0) * PTS + p] - e.x;
            float d1 = zt[(c + 1) * PTS + p] - e.y;
            float d2 = zt[(c + 2) * PTS + p] - e.z;
            float d3 = zt[(c + 3) * PTS + p] - e.w;
            lsum += d0 * d0 + d1 * d1 + d2 * d2 + d3 * d3;
        }
    }
#pragma unroll
    for (int off = 32; off > 0; off >>= 1) lsum += __shfl_down(lsum, off, 64);
    if ((t & 63) == 0) atomicAdd(loss_acc, lsum);
}

// ---------------- finalize ----------------
__global__ __launch_bounds__(1024) void vq_final(const float* __restrict__ counts,
                                                 const float* __restrict__ loss_acc,
                                                 float* __restrict__ out_loss,
                                                 float* __restrict__ out_perp) {
    __shared__ float red[16];
    int t = threadIdx.x;
    float cnt = counts[t];
    float avg = cnt * (1.0f / (float)Npts);
    float term = avg * logf(avg + 1e-10f);
#pragma unroll
    for (int off = 32; off > 0; off >>= 1) term += __shfl_down(term, off, 64);
    if ((t & 63) == 0) red[t >> 6] = term;
    __syncthreads();
    if (t == 0) {
        float s = 0.f;
        for (int i = 0; i < 16; ++i) s += red[i];
        *out_perp = expf(-s);
        *out_loss = BETA * loss_acc[0] * (1.0f / 16777216.0f);
    }
}

extern "C" void kernel_launch(void* const* d_in, const int* in_sizes, int n_in,
                              void* d_out, int out_size, void* d_ws, size_t ws_size,
                              hipStream_t stream) {
    const float* z     = (const float*)d_in[0];
    const float* embed = (const float*)d_in[1];

    float* ws       = (float*)d_ws;
    float* loss_acc = ws;            // [0]
    float* counts   = ws + 64;       // [1024]
    float* enorm    = ws + 2048;     // [1024]

    float* out_zq   = (float*)d_out;
    float* out_idx  = out_zq + (size_t)Npts * Cdim;
    float* out_loss = out_idx + Npts;
    float* out_perp = out_loss + 1;

    if (ws_size >= WS_NEED) {
        f16* Bws = (f16*)((char*)d_ws + 65536);
        prep_kernel<<<512, 256, 0, stream>>>(embed, Bws, enorm, ws);  // +enorm +zero
        vq_gemm<<<Npts / MT, 512, 0, stream>>>(z, Bws, enorm, out_idx,
                                               loss_acc, counts);
        vq_epi<<<Npts / 64, 256, 0, stream>>>(embed, out_idx, out_zq);
    } else {
        hipMemsetAsync(d_ws, 0, 2048 * sizeof(float), stream);
        enorm_kernel<<<NCODES / 256, 256, 0, stream>>>(embed, enorm);
        vq_main_fb<<<Npts / PTS, 256, 0, stream>>>(z, embed, enorm, out_zq, out_idx,
                                                   loss_acc, counts);
    }
    vq_final<<<1, 1024, 0, stream>>>(counts, loss_acc, out_loss, out_perp);
}

// Round 19
// 187.764 us; speedup vs baseline: 7.2661x; 1.0089x over previous
//
#include <hip/hip_runtime.h>
#include <math.h>

#define Cdim   256
#define Ssp    8192      // D*H*W
#define Npts   65536
#define NCODES 1024
#define BETA   0.25f
#define MT     128       // points per GEMM block
#define ESCALE 8192.0f   // keep el out of f16-subnormal truncation
#define WS_NEED (65536 + (size_t)786432 * 2)

typedef _Float16 f16;
typedef f16   half8  __attribute__((ext_vector_type(8)));
typedef float f32x16 __attribute__((ext_vector_type(16)));

#define MFMA16(A, B, C) __builtin_amdgcn_mfma_f32_32x32x16_f16(A, B, C, 0, 0, 0)

// ---------------- enorm (standalone, used by fallback path only) ----------------
__global__ __launch_bounds__(256) void enorm_kernel(const float* __restrict__ embed,
                                                    float* __restrict__ enorm) {
    int j = blockIdx.x * 256 + threadIdx.x;
    if (j >= NCODES) return;
    const float4* row = reinterpret_cast<const float4*>(embed + (size_t)j * Cdim);
    float s = 0.f;
#pragma unroll 8
    for (int c4 = 0; c4 < Cdim / 4; ++c4) {
        float4 v = row[c4];
        s += v.x * v.x + v.y * v.y + v.z * v.z + v.w * v.w;
    }
    enorm[j] = s;
}

// ---------------- prep: split embed into f16 hi/lo + enorm + ws zero (fused) ----------------
// Bws: [kc=32][code=1024][k'=16] f16. kc 0..15 -> eh, kc 16..31 -> el. (r16, verified)
__global__ __launch_bounds__(256) void prep_kernel(const float* __restrict__ embed,
                                                   f16* __restrict__ Bws,
                                                   float* __restrict__ enorm,
                                                   float* __restrict__ wszero) {
    int tid = blockIdx.x * 256 + threadIdx.x;
    int o4 = tid * 4;
    int kc = o4 >> 14;
    int r  = o4 & 16383;
    int j  = r >> 4;
    int k0 = r & 15;
#pragma unroll
    for (int i = 0; i < 4; ++i) {
        int k = kc * 16 + k0 + i;
        int c = k & 255;
        float ev = embed[j * 256 + c] * ESCALE;
        f16 eh = (f16)ev;
        f16 v  = (k >= 256) ? (f16)(ev - (float)eh) : eh;
        Bws[o4 + i] = v;
    }
    if (blockIdx.x < 4) {
        const int je = blockIdx.x * 256 + threadIdx.x;
        const float4* row = reinterpret_cast<const float4*>(embed + (size_t)je * Cdim);
        float s = 0.f;
#pragma unroll 8
        for (int c4 = 0; c4 < Cdim / 4; ++c4) {
            float4 v = row[c4];
            s += v.x * v.x + v.y * v.y + v.z * v.z + v.w * v.w;
        }
        enorm[je] = s;
    } else if (blockIdx.x == 4) {
        for (int i = threadIdx.x; i < 2048; i += 256) wszero[i] = 0.f;  // loss + counts
    }
}

// ---------------- MFMA GEMM + fused argmin + loss (v13: fused E+L, 24-MFMA clusters) ----------------
// r16 skeleton (512 thr / 8 waves = 2m x 4n, MT=128, 2 jh halves, A=[zh|zl] 128KB
// LDS XOR-swz, B global->reg pinned ping-pong + setprio). Phases E and L fused:
// per chunk kc read {H,L} A-frags ONCE + Beh(kc) + Bel(16+kc), then one 24-MFMA
// cluster (H*Beh x8, L*Beh x8, H*Bel x8). A-LDS traffic -25%, cluster length 1.5x.
__global__ __launch_bounds__(512, 2) void vq_gemm(const float* __restrict__ z,
                                                  const f16* __restrict__ Bws,
                                                  const float* __restrict__ enorm,
                                                  float* __restrict__ out_idx,
                                                  float* __restrict__ loss_acc,
                                                  float* __restrict__ counts) {
    __shared__ __attribute__((aligned(16))) f16 As[MT * 512];   // 128 KB
    __shared__ float en_s[NCODES];
    __shared__ float znp[4 * MT];
    __shared__ float zn_s[MT];
    __shared__ float redv[8 * MT];
    __shared__ int   redi[8 * MT];

    const int t  = threadIdx.x;
    const int l  = t & 63;
    const int w  = t >> 6;
    const int wm = w >> 2;
    const int wn = w & 3;
    const int ln = l & 31;
    const int kb = l >> 5;
    const int n0 = blockIdx.x * MT;
    const int b  = n0 >> 13;
    const int s0 = n0 & 8191;

    // ---- stage A (zh granules 0..31, zl 32..63, swizzle g^=(p&7)) ----
    {
        const int p = t & 127;
        const int q = t >> 7;
        const float* zb = z + (size_t)b * ((size_t)Cdim * Ssp) + s0;
        float zsq = 0.f;
#pragma unroll
        for (int gi = 0; gi < 8; ++gi) {
            const int c0 = q * 64 + gi * 8;
            half8 hh, ll;
#pragma unroll
            for (int u = 0; u < 8; ++u) {     // c ascending -> zsq order == rounds 2/5-18
                float zv = zb[(size_t)(c0 + u) * Ssp + p];
                zsq += zv * zv;
                f16 zh = (f16)zv;
                hh[u] = zh;
                ll[u] = (f16)(zv - (float)zh);
            }
            const int g0 = c0 >> 3;
            *(half8*)&As[p * 512 + 8 * (g0 ^ (p & 7))]        = hh;
            *(half8*)&As[p * 512 + 8 * ((32 + g0) ^ (p & 7))] = ll;
        }
        znp[q * MT + p] = zsq;
    }
    for (int i = t; i < NCODES; i += 512) en_s[i] = enorm[i];
    __syncthreads();
    if (t < MT)
        zn_s[t] = ((znp[t] + znp[MT + t]) + znp[2 * MT + t]) + znp[3 * MT + t];
    __syncthreads();

    const int rowA = wm * 64 + ln;

    // fused load group: {H,L} A-frags + Beh(kcv) + Bel(16+kcv)  (kcv clamped to 0..15)
#define LOADF(kcv, H0, H1, L0, L1, E0, E1, E2, E3, F0, F1, F2, F3)       \
    {                                                                    \
        const int kcl_ = ((kcv) < 16) ? (kcv) : 15;                      \
        const int gz   = 2 * kcl_ + kb;                                  \
        const int gwh  = 8 * (gz ^ (ln & 7));                            \
        const int gwl  = 8 * ((32 + gz) ^ (ln & 7));                     \
        H0 = *(const half8*)&As[rowA * 512 + gwh];                       \
        H1 = *(const half8*)&As[(rowA + 32) * 512 + gwh];                \
        L0 = *(const half8*)&As[rowA * 512 + gwl];                       \
        L1 = *(const half8*)&As[(rowA + 32) * 512 + gwl];                \
        const f16* se = bbase + (size_t)kcl_ * 16384;                    \
        E0 = *(const half8*)(se);                                        \
        E1 = *(const half8*)(se + 512);                                  \
        E2 = *(const half8*)(se + 1024);                                 \
        E3 = *(const half8*)(se + 1536);                                 \
        const f16* sf = bbase + (size_t)(16 + kcl_) * 16384;             \
        F0 = *(const half8*)(sf);                                        \
        F1 = *(const half8*)(sf + 512);                                  \
        F2 = *(const half8*)(sf + 1024);                                 \
        F3 = *(const half8*)(sf + 1536);                                 \
    }

    // fused 24-MFMA cluster: zh*eh (8), zl*eh (8), zh*el (8)
#define MFMAF(H0, H1, L0, L1, E0, E1, E2, E3, F0, F1, F2, F3)            \
    __builtin_amdgcn_s_setprio(1);                                       \
    acc[0][0] = MFMA16(H0, E0, acc[0][0]);                               \
    acc[1][0] = MFMA16(H1, E0, acc[1][0]);                               \
    acc[0][1] = MFMA16(H0, E1, acc[0][1]);                               \
    acc[1][1] = MFMA16(H1, E1, acc[1][1]);                               \
    acc[0][2] = MFMA16(H0, E2, acc[0][2]);                               \
    acc[1][2] = MFMA16(H1, E2, acc[1][2]);                               \
    acc[0][3] = MFMA16(H0, E3, acc[0][3]);                               \
    acc[1][3] = MFMA16(H1, E3, acc[1][3]);                               \
    acc[0][0] = MFMA16(L0, E0, acc[0][0]);                               \
    acc[1][0] = MFMA16(L1, E0, acc[1][0]);                               \
    acc[0][1] = MFMA16(L0, E1, acc[0][1]);                               \
    acc[1][1] = MFMA16(L1, E1, acc[1][1]);                               \
    acc[0][2] = MFMA16(L0, E2, acc[0][2]);                               \
    acc[1][2] = MFMA16(L1, E2, acc[1][2]);                               \
    acc[0][3] = MFMA16(L0, E3, acc[0][3]);                               \
    acc[1][3] = MFMA16(L1, E3, acc[1][3]);                               \
    acc[0][0] = MFMA16(H0, F0, acc[0][0]);                               \
    acc[1][0] = MFMA16(H1, F0, acc[1][0]);                               \
    acc[0][1] = MFMA16(H0, F1, acc[0][1]);                               \
    acc[1][1] = MFMA16(H1, F1, acc[1][1]);                               \
    acc[0][2] = MFMA16(H0, F2, acc[0][2]);                               \
    acc[1][2] = MFMA16(H1, F2, acc[1][2]);                               \
    acc[0][3] = MFMA16(H0, F3, acc[0][3]);                               \
    acc[1][3] = MFMA16(H1, F3, acc[1][3]);                               \
    __builtin_amdgcn_s_setprio(0);

#define SB __builtin_amdgcn_sched_barrier(0);

#pragma unroll 1
    for (int jh = 0; jh < 2; ++jh) {
        f32x16 acc[2][4] = {};
        const f16* bbase = Bws + (size_t)(jh * 512 + wn * 128 + ln) * 16 + kb * 8;

        half8 hA0, hA1, lA0, lA1, eA0, eA1, eA2, eA3, fA0, fA1, fA2, fA3;
        half8 hB0, hB1, lB0, lB1, eB0, eB1, eB2, eB3, fB0, fB1, fB2, fB3;
        LOADF(0, hA0, hA1, lA0, lA1, eA0, eA1, eA2, eA3, fA0, fA1, fA2, fA3)

#pragma unroll 1
        for (int kc = 0; kc < 16; kc += 2) {
            LOADF(kc + 1, hB0, hB1, lB0, lB1, eB0, eB1, eB2, eB3, fB0, fB1, fB2, fB3)
            SB
            MFMAF(hA0, hA1, lA0, lA1, eA0, eA1, eA2, eA3, fA0, fA1, fA2, fA3)
            SB
            LOADF(kc + 2, hA0, hA1, lA0, lA1, eA0, eA1, eA2, eA3, fA0, fA1, fA2, fA3)
            SB
            MFMAF(hB0, hB1, lB0, lB1, eB0, eB1, eB2, eB3, fB0, fB1, fB2, fB3)
            SB
        }

        // ---- scores + per-half argmin. C layout: col=lane&31,
        //      row=(reg&3)+8*(reg>>2)+4*(lane>>5)  (verified rounds 5-18) ----
        const int h = l >> 5;
#pragma unroll
        for (int mm = 0; mm < 2; ++mm) {
#pragma unroll
            for (int rg = 0; rg < 16; ++rg) {
                const int row = wm * 64 + mm * 32 + (rg & 3) + 8 * (rg >> 2) + 4 * h;
                const float znv = zn_s[row];
                float bv = 3.0e38f; int bi = 0;
#pragma unroll
                for (int nn = 0; nn < 4; ++nn) {
                    const int col = jh * 512 + wn * 128 + nn * 32 + ln;
                    float k1 = znv + en_s[col];
                    float sc = k1 - acc[mm][nn][rg] * (2.0f / ESCALE);
                    if (sc < bv) { bv = sc; bi = col; }
                }
#pragma unroll
                for (int off = 1; off < 32; off <<= 1) {
                    float ov = __shfl_xor(bv, off, 64);
                    int   oi = __shfl_xor(bi, off, 64);
                    if (ov < bv || (ov == bv && oi < bi)) { bv = ov; bi = oi; }
                }
                if (ln == 0) {
                    redv[(jh * 4 + wn) * MT + row] = bv;
                    redi[(jh * 4 + wn) * MT + row] = bi;
                }
            }
        }
    }
    __syncthreads();

    // ---- final argmin; index/count; loss = sum of best scores ----
    if (t < MT) {
        float bv = redv[t]; int bi = redi[t];
#pragma unroll
        for (int s = 1; s < 8; ++s) {
            float ov = redv[s * MT + t]; int oi = redi[s * MT + t];
            if (ov < bv || (ov == bv && oi < bi)) { bv = ov; bi = oi; }
        }
        out_idx[n0 + t] = (float)bi;
        atomicAdd(&counts[bi], 1.0f);
        float lsum = bv;
#pragma unroll
        for (int off = 32; off > 0; off >>= 1) lsum += __shfl_down(lsum, off, 64);
        if ((t & 63) == 0) atomicAdd(loss_acc, lsum);
    }
#undef LOADF
#undef MFMAF
#undef SB
}

// ---------------- epilogue: z_q gather-write, 4x wave-parallelism (r18, verified) ----------------
__global__ __launch_bounds__(256) void vq_epi(const float* __restrict__ embed,
                                              const float* __restrict__ out_idx,
                                              float* __restrict__ out_zq) {
    const int t  = threadIdx.x;
    const int n0 = blockIdx.x * 64;
    const int b  = n0 >> 13, s0 = n0 & 8191;
    const int p  = t & 63;
    const int cq = t >> 6;
    const int idx = (int)out_idx[n0 + p];
    const float4* er = reinterpret_cast<const float4*>(embed + (size_t)idx * Cdim);
    float* oq = out_zq + (size_t)b * ((size_t)Cdim * Ssp) + s0 + p;
#pragma unroll 4
    for (int pass = 0; pass < 16; ++pass) {
        const int c = cq * 64 + pass * 4;
        float4 e = er[c >> 2];
        __builtin_nontemporal_store(e.x, oq + (size_t)(c + 0) * Ssp);
        __builtin_nontemporal_store(e.y, oq + (size_t)(c + 1) * Ssp);
        __builtin_nontemporal_store(e.z, oq + (size_t)(c + 2) * Ssp);
        __builtin_nontemporal_store(e.w, oq + (size_t)(c + 3) * Ssp);
    }
}

// ================= fallback (round-4 verified kernel, used if ws too small) =================
#define PTS 64
#define CT  128
#define KC  32
__global__ __launch_bounds__(256, 2) void vq_main_fb(const float* __restrict__ z,
                                                     const float* __restrict__ embed,
                                                     const float* __restrict__ enorm,
                                                     float* __restrict__ out_zq,
                                                     float* __restrict__ out_idx,
                                                     float* __restrict__ loss_acc,
                                                     float* __restrict__ counts) {
    __shared__ __attribute__((aligned(16))) float smem[Cdim * PTS + KC * CT];
    float* zt = smem;
    float* et = smem + Cdim * PTS;
    const int t  = threadIdx.x;
    const int n0 = blockIdx.x * PTS;
    const int b  = n0 >> 13;
    const int s0 = n0 & 8191;
    const float* zb = z + (size_t)b * Cdim * Ssp + s0;
    {
        const int p4 = (t & 15) * 4, crow = t >> 4;
#pragma unroll
        for (int it = 0; it < 16; ++it) {
            int c = it * 16 + crow;
            float4 v = *reinterpret_cast<const float4*>(zb + (size_t)c * Ssp + p4);
            *reinterpret_cast<float4*>(&zt[c * PTS + p4]) = v;
        }
    }
    __syncthreads();
    {
        const int p = t & 63, qq = t >> 6;
        float sacc = 0.f;
#pragma unroll 8
        for (int c = qq * 64; c < qq * 64 + 64; ++c) { float v = zt[c * PTS + p]; sacc += v * v; }
        et[qq * 64 + p] = sacc;
    }
    __syncthreads();
    const int pg = t & 15, jg = t >> 4;
    const int p0 = pg * 4;
    float zn[4];
#pragma unroll
    for (int i = 0; i < 4; ++i) {
        int p = p0 + i;
        zn[i] = ((et[p] + et[64 + p]) + et[128 + p]) + et[192 + p];
    }
    float bestv[4] = {3.0e38f, 3.0e38f, 3.0e38f, 3.0e38f};
    int   besti[4] = {0, 0, 0, 0};
    const int dj = t >> 3, q = t & 7;
    const int sw_st = (q & 3) << 3;
    for (int jt = 0; jt < NCODES / CT; ++jt) {
        const int J0 = jt * CT;
        float acc[4][8];
#pragma unroll
        for (int i = 0; i < 4; ++i)
#pragma unroll
            for (int m = 0; m < 8; ++m) acc[i][m] = 0.f;
        for (int ks = 0; ks < Cdim / KC; ++ks) {
            const int cc0 = ks * KC;
            __syncthreads();
#pragma unroll
            for (int i = 0; i < 4; ++i) {
                const int jrel = dj + 32 * i;
                const float4 v = *reinterpret_cast<const float4*>(
                    embed + (size_t)(J0 + jrel) * Cdim + cc0 + q * 4);
                const int c0 = q * 4;
                const int jsw = jrel ^ sw_st;
                et[(c0 + 0) * CT + jsw] = v.x;
                et[(c0 + 1) * CT + jsw] = v.y;
                et[(c0 + 2) * CT + jsw] = v.z;
                et[(c0 + 3) * CT + jsw] = v.w;
            }
            __syncthreads();
#pragma unroll 4
            for (int c = 0; c < KC; ++c) {
                const float4 zp = *reinterpret_cast<const float4*>(&zt[(cc0 + c) * PTS + p0]);
                const int jb = (jg * 8) ^ (((c >> 2) & 3) << 3);
                const float4 ea = *reinterpret_cast<const float4*>(&et[c * CT + jb]);
                const float4 eb = *reinterpret_cast<const float4*>(&et[c * CT + jb + 4]);
                const float zc[4] = {zp.x, zp.y, zp.z, zp.w};
                const float ec[8] = {ea.x, ea.y, ea.z, ea.w, eb.x, eb.y, eb.z, eb.w};
#pragma unroll
                for (int i = 0; i < 4; ++i)
#pragma unroll
                    for (int m = 0; m < 8; ++m) acc[i][m] += zc[i] * ec[m];
            }
        }
#pragma unroll
        for (int m = 0; m < 8; ++m) {
            const int cid = J0 + jg * 8 + m;
            const float en = enorm[cid];
#pragma unroll
            for (int i = 0; i < 4; ++i) {
                float k1 = zn[i] + en;
                float sc = k1 - 2.0f * acc[i][m];
                if (sc < bestv[i]) { bestv[i] = sc; besti[i] = cid; }
            }
        }
    }
    __syncthreads();
    float* rv = et; int* ri = (int*)(et + 1024); int* idxf = (int*)(et + 2048);
#pragma unroll
    for (int i = 0; i < 4; ++i) { int p = p0 + i; rv[p * 16 + jg] = bestv[i]; ri[p * 16 + jg] = besti[i]; }
    __syncthreads();
    if (t < PTS) {
        int p = t;
        float bv = rv[p * 16]; int bi = ri[p * 16];
        for (int g = 1; g < 16; ++g) {
            float v = rv[p * 16 + g]; int ii = ri[p * 16 + g];
            if (v < bv || (v == bv && ii < bi)) { bv = v; bi = ii; }
        }
        idxf[p] = bi;
        out_idx[n0 + p] = (float)bi;
        atomicAdd(&counts[bi], 1.0f);
    }
    __syncthreads();
    float lsum = 0.f;
    {
        const int p = t & 63, cbase = t >> 6;
        const int myidx = idxf[p];
        const float4* erow4 = reinterpret_cast<const float4*>(embed + (size_t)myidx * Cdim);
        float* ob = out_zq + (size_t)b * Cdim * Ssp + s0 + p;
#pragma unroll 4
        for (int pass = 0; pass < 16; ++pass) {
            int c = cbase * 64 + pass * 4;
            float4 e = erow4[c >> 2];
            ob[(size_t)(c + 0) * Ssp] = e.x;
            ob[(size_t)(c + 1) * Ssp] = e.y;
            ob[(size_t)(c + 2) * Ssp] = e.z;
            ob[(size_t)(c + 3) * Ssp] = e.w;
            float d0 = zt[(c + 0) * PTS + p] - e.x;
            float d1 = zt[(c + 1) * PTS + p] - e.y;
            float d2 = zt[(c + 2) * PTS + p] - e.z;
            float d3 = zt[(c + 3) * PTS + p] - e.w;
            lsum += d0 * d0 + d1 * d1 + d2 * d2 + d3 * d3;
        }
    }
#pragma unroll
    for (int off = 32; off > 0; off >>= 1) lsum += __shfl_down(lsum, off, 64);
    if ((t & 63) == 0) atomicAdd(loss_acc, lsum);
}

// ---------------- finalize ----------------
__global__ __launch_bounds__(1024) void vq_final(const float* __restrict__ counts,
                                                 const float* __restrict__ loss_acc,
                                                 float* __restrict__ out_loss,
                                                 float* __restrict__ out_perp) {
    __shared__ float red[16];
    int t = threadIdx.x;
    float cnt = counts[t];
    float avg = cnt * (1.0f / (float)Npts);
    float term = avg * logf(avg + 1e-10f);
#pragma unroll
    for (int off = 32; off > 0; off >>= 1) term += __shfl_down(term, off, 64);
    if ((t & 63) == 0) red[t >> 6] = term;
    __syncthreads();
    if (t == 0) {
        float s = 0.f;
        for (int i = 0; i < 16; ++i) s += red[i];
        *out_perp = expf(-s);
        *out_loss = BETA * loss_acc[0] * (1.0f / 16777216.0f);
    }
}

extern "C" void kernel_launch(void* const* d_in, const int* in_sizes, int n_in,
                              void* d_out, int out_size, void* d_ws, size_t ws_size,
                              hipStream_t stream) {
    const float* z     = (const float*)d_in[0];
    const float* embed = (const float*)d_in[1];

    float* ws       = (float*)d_ws;
    float* loss_acc = ws;            // [0]
    float* counts   = ws + 64;       // [1024]
    float* enorm    = ws + 2048;     // [1024]

    float* out_zq   = (float*)d_out;
    float* out_idx  = out_zq + (size_t)Npts * Cdim;
    float* out_loss = out_idx + Npts;
    float* out_perp = out_loss + 1;

    if (ws_size >= WS_NEED) {
        f16* Bws = (f16*)((char*)d_ws + 65536);
        prep_kernel<<<512, 256, 0, stream>>>(embed, Bws, enorm, ws);
        vq_gemm<<<Npts / MT, 512, 0, stream>>>(z, Bws, enorm, out_idx,
                                               loss_acc, counts);
        vq_epi<<<Npts / 64, 256, 0, stream>>>(embed, out_idx, out_zq);
    } else {
        hipMemsetAsync(d_ws, 0, 2048 * sizeof(float), stream);
        enorm_kernel<<<NCODES / 256, 256, 0, stream>>>(embed, enorm);
        vq_main_fb<<<Npts / PTS, 256, 0, stream>>>(z, embed, enorm, out_zq, out_idx,
                                                   loss_acc, counts);
    }
    vq_final<<<1, 1024, 0, stream>>>(counts, loss_acc, out_loss, out_perp);
}